// Round 10
// baseline (257.494 us; speedup 1.0000x reference)
//
#include <hip/hip_runtime.h>
#include <hip/hip_bf16.h>
#include <math.h>

#define NB  1024
#define NN  1000
#define NE  128
#define NH  8
#define NDK 16
#define NSC 256

typedef __attribute__((ext_vector_type(4))) float f32x4;

__device__ __forceinline__ f32x4 ld4(const float* p) {
    return *reinterpret_cast<const f32x4*>(p);
}

// ---------------- single fused kernel: one block per b ----------------
// query (in-block) -> 8 heads attention (dense sequential K/V stream) -> logits tail.
// No workspace, no cross-block communication. 512 thr = 8 waves; grid 1024 = 4 blocks/CU.
__global__ __launch_bounds__(512, 4)
void fused_kernel(const float* __restrict__ ctx, const float* __restrict__ stepc,
                  const float* __restrict__ Wstep,
                  const float* __restrict__ gK, const float* __restrict__ gV,
                  const float* __restrict__ lK, const float* __restrict__ Wout,
                  const unsigned char* __restrict__ mask,
                  __hip_bfloat16* __restrict__ out)
{
    const int b = blockIdx.x;
    const int t = threadIdx.x;
    const int w = t >> 6, lane = t & 63;
    const int qq  = lane & 3;             // dk-quarter 0..3
    const int rsl = lane >> 2;            // row slot 0..15

    __shared__ __align__(16) float q_lds[NE];
    __shared__ float wmax[2][8], wsum[2][8];
    __shared__ __align__(16) float wred[2][8][16];
    __shared__ __align__(16) float g[NE];       // concat heads
    __shared__ __align__(16) float gout[NE];
    __shared__ float red[8];
    __shared__ float Mv, LSv;

    // mask dtype detect (wave-uniform): first 64 words all <=1 -> int32 mask
    const unsigned int* mw = reinterpret_cast<const unsigned int*>(mask);
    const bool m_i32 = (__ballot(mw[lane] <= 1u) == ~0ull);
    const int* mask_i = reinterpret_cast<const int*>(mask);

    // ---- query rows w*16..w*16+15 (wave w), shfl-butterfly dot (R5-proven) ----
    {
        const f32x4 sv = ld4(stepc + (size_t)b * NSC + lane * 4);
        #pragma unroll
        for (int r = 0; r < 16; ++r) {
            const int row = w * NDK + r;
            f32x4 wv = ld4(Wstep + (size_t)row * NSC + lane * 4);
            float p = wv.x * sv.x + wv.y * sv.y + wv.z * sv.z + wv.w * sv.w;
            #pragma unroll
            for (int off = 32; off > 0; off >>= 1) p += __shfl_xor(p, off);
            if (lane == 0) q_lds[row] = p + ctx[(size_t)b * NE + row];
        }
    }

    // ---- row-mask bits: loaded once, reused by all 8 heads ----
    unsigned mbits = 0;
    #pragma unroll
    for (int i = 0; i < 8; ++i) {
        const int n = w * 16 + i * 128 + rsl;
        const bool dead = (n >= NN);
        const int nn = dead ? 0 : n;
        int mk = m_i32 ? (mask_i[(size_t)b * NN + nn] != 0)
                       : (mask[(size_t)b * NN + nn] != 0);
        mbits |= (unsigned)(mk | (dead ? 1 : 0)) << i;
    }
    __syncthreads();                      // q_lds ready

    // ---- attention, head-sequential; DENSE sequential K/V stream ----
    #pragma unroll 1
    for (int h = 0; h < NH; ++h) {
        const int pb = h & 1;
        const f32x4 qv = ld4(&q_lds[h * NDK + qq * 4]);
        const float* Kb = gK + (size_t)(h * NB + b) * NN * NDK;
        const float* Vb = gV + (size_t)(h * NB + b) * NN * NDK;

        f32x4 vreg[8];
        float sc[8];
        #pragma unroll
        for (int i = 0; i < 8; ++i) {
            const int n = w * 16 + i * 128 + rsl;
            const int nn = (n < NN) ? n : 0;            // dense: only clamp dead rows
            const size_t off = (size_t)nn * NDK + qq * 4;
            f32x4 kv = ld4(Kb + off);
            vreg[i] = ld4(Vb + off);
            sc[i] = kv.x*qv.x + kv.y*qv.y + kv.z*qv.z + kv.w*qv.w;
        }
        #pragma unroll
        for (int i = 0; i < 8; ++i) {
            float p = sc[i];
            p += __shfl_xor(p, 1);
            p += __shfl_xor(p, 2);          // all 4 quad lanes hold full dot
            sc[i] = ((mbits >> i) & 1u) ? -INFINITY : p * 0.25f;   // 1/sqrt(16)
        }

        float m = sc[0];
        #pragma unroll
        for (int i = 1; i < 8; ++i) m = fmaxf(m, sc[i]);
        #pragma unroll
        for (int off = 32; off > 0; off >>= 1) m = fmaxf(m, __shfl_xor(m, off));
        if (lane == 0) wmax[pb][w] = m;
        __syncthreads();
        float M = wmax[pb][0];
        #pragma unroll
        for (int i = 1; i < 8; ++i) M = fmaxf(M, wmax[pb][i]);

        f32x4 acc = {0.f, 0.f, 0.f, 0.f};
        float ls = 0.f;
        #pragma unroll
        for (int i = 0; i < 8; ++i) {
            const float e = expf(sc[i] - M);   // exp(-inf)=0 for masked
            ls += e;
            acc.x += e * vreg[i].x; acc.y += e * vreg[i].y;
            acc.z += e * vreg[i].z; acc.w += e * vreg[i].w;
        }
        #pragma unroll
        for (int off = 32; off > 0; off >>= 1) ls += __shfl_xor(ls, off);
        if (lane == 0) wsum[pb][w] = ls;       // = 4 * true wave sum (quad duplication)

        #pragma unroll
        for (int off = 4; off < 64; off <<= 1) {
            acc.x += __shfl_xor(acc.x, off);
            acc.y += __shfl_xor(acc.y, off);
            acc.z += __shfl_xor(acc.z, off);
            acc.w += __shfl_xor(acc.w, off);
        }
        if (lane < 4) *reinterpret_cast<f32x4*>(&wred[pb][w][lane * 4]) = acc;
        __syncthreads();

        if (t < NDK) {
            float S = wsum[pb][0];
            #pragma unroll
            for (int i = 1; i < 8; ++i) S += wsum[pb][i];
            S *= 0.25f;
            float r = wred[pb][0][t];
            #pragma unroll
            for (int i = 1; i < 8; ++i) r += wred[pb][i][t];
            g[h * NDK + t] = r / S;
        }
        // next head uses the other parity buffers; g-write lands before next barrier
    }
    __syncthreads();                            // g[128] complete

    // ---------------- logits tail (proven structure) ----------------
    if (t < NE) {
        float a2 = 0.f;
        const float4* w4 = reinterpret_cast<const float4*>(Wout + (size_t)t * NE);
        const float4* g4 = reinterpret_cast<const float4*>(g);
        #pragma unroll 8
        for (int e4 = 0; e4 < NE / 4; ++e4) {
            float4 wv = w4[e4]; float4 gg = g4[e4];
            a2 += wv.x*gg.x + wv.y*gg.y + wv.z*gg.z + wv.w*gg.w;
        }
        gout[t] = a2;
    }
    __syncthreads();

    const f32x4* go4 = reinterpret_cast<const f32x4*>(gout);
    float lv[2];
    #pragma unroll
    for (int i = 0; i < 2; ++i) {
        const int n = t + 512 * i;
        const bool live = (n < NN);
        const int nidx = live ? n : 0;
        int mkd = m_i32 ? (mask_i[(size_t)b * NN + nidx] != 0)
                        : (mask[(size_t)b * NN + nidx] != 0);
        mkd |= (live ? 0 : 1);
        const int nn = mkd ? 0 : n;            // keep skip: lK granule is 512B (efficient)
        const float* lp = lK + ((size_t)b * NN + nn) * NE;
        float a3 = 0.f;
        #pragma unroll
        for (int c4 = 0; c4 < NE / 4; ++c4) {
            f32x4 x = ld4(lp + 4 * c4);
            f32x4 gv = go4[c4];                 // broadcast LDS read
            a3 += x.x*gv.x + x.y*gv.y + x.z*gv.z + x.w*gv.w;
        }
        float val = tanhf(a3 * 0.08838834764831845f) * 10.0f;  // 1/sqrt(128), clip 10
        lv[i] = mkd ? -3.0e38f : val;   // finite sentinel (NaN-free compare vs ref -inf)
    }

    float mm = fmaxf(lv[0], lv[1]);
    #pragma unroll
    for (int off = 32; off > 0; off >>= 1) mm = fmaxf(mm, __shfl_xor(mm, off));
    if (lane == 0) red[w] = mm;
    __syncthreads();
    if (t == 0) {
        float m2 = red[0];
        #pragma unroll
        for (int i = 1; i < 8; ++i) m2 = fmaxf(m2, red[i]);
        Mv = m2;
    }
    __syncthreads();
    const float M2 = Mv;
    float s2 = expf(lv[0] - M2) + expf(lv[1] - M2);   // exp(-3e38 - M) == 0
    #pragma unroll
    for (int off = 32; off > 0; off >>= 1) s2 += __shfl_xor(s2, off);
    if (lane == 0) red[w] = s2;
    __syncthreads();
    if (t == 0) {
        float ss = 0.f;
        #pragma unroll
        for (int i = 0; i < 8; ++i) ss += red[i];
        LSv = M2 + logf(ss);
    }
    __syncthreads();
    const float LS = LSv;
    #pragma unroll
    for (int i = 0; i < 2; ++i) {
        const int n = t + 512 * i;
        if (n < NN)
            out[(size_t)b * NN + n] = __float2bfloat16(lv[i] - LS);  // -3e38-LS stays -3e38
    }
}

extern "C" void kernel_launch(void* const* d_in, const int* in_sizes, int n_in,
                              void* d_out, int out_size, void* d_ws, size_t ws_size,
                              hipStream_t stream) {
    const float* ctx   = (const float*)d_in[0];
    const float* stepc = (const float*)d_in[1];
    const float* Wstep = (const float*)d_in[2];
    const float* gK    = (const float*)d_in[3];
    const float* gV    = (const float*)d_in[4];
    const float* lK    = (const float*)d_in[5];
    const float* Wout  = (const float*)d_in[6];
    const unsigned char* mask = (const unsigned char*)d_in[7];
    __hip_bfloat16* out = (__hip_bfloat16*)d_out;

    fused_kernel<<<dim3(NB), dim3(512), 0, stream>>>(
        ctx, stepc, Wstep, gK, gV, lK, Wout, mask, out);
}